// Round 5
// baseline (837.927 us; speedup 1.0000x reference)
//
#include <hip/hip_runtime.h>
#include <hip/hip_bf16.h>
#include <math.h>

#define N_DIN 256      // D_IN
#define N_COUT 256     // H*D_OUT
#define NEG_SLOPE 0.2f
#define L2E 1.44269504f   // log2(e)

typedef _Float16 f16;
typedef f16 f16x2 __attribute__((ext_vector_type(2)));
typedef f16 f16x4 __attribute__((ext_vector_type(4)));
typedef f16 f16x8 __attribute__((ext_vector_type(8)));
typedef float f32x4 __attribute__((ext_vector_type(4)));

// ---------------- fp32 -> fp16 conversion (feat, Wsrc, Wdst) + cursor zeroing ----------------
// grid: [0,6250) feat, [6250,6282) Wsrc, [6282,6314) Wdst, [6314,...) zero cursor
__global__ __launch_bounds__(256) void convert_all(
    const float* __restrict__ feat, const float* __restrict__ Wsrc,
    const float* __restrict__ Wdst, f16* __restrict__ feat_h,
    f16* __restrict__ wsrc_h, f16* __restrict__ wdst_h,
    int* __restrict__ cursor, int n)
{
    const int b = blockIdx.x;
    if (b >= 6314) {
        int i = (b - 6314) * 256 + threadIdx.x;
        if (i < n) cursor[i] = 0;
        return;
    }
    const float* __restrict__ in;
    f16* __restrict__ out;
    size_t base;
    if (b < 6250)      { in = feat; out = feat_h; base = (size_t)b * 2048; }
    else if (b < 6282) { in = Wsrc; out = wsrc_h; base = (size_t)(b - 6250) * 2048; }
    else               { in = Wdst; out = wdst_h; base = (size_t)(b - 6282) * 2048; }
    size_t i = base + (size_t)threadIdx.x * 8;
    float4 v0 = *reinterpret_cast<const float4*>(&in[i]);
    float4 v1 = *reinterpret_cast<const float4*>(&in[i + 4]);
    f16x8 o;
    o[0] = (f16)v0.x; o[1] = (f16)v0.y; o[2] = (f16)v0.z; o[3] = (f16)v0.w;
    o[4] = (f16)v1.x; o[5] = (f16)v1.y; o[6] = (f16)v1.z; o[7] = (f16)v1.w;
    *reinterpret_cast<f16x8*>(&out[i]) = o;
}

// ---------------- fp16 MFMA projection + fused degree count ----------------
// blocks [0,nproj): 64-row tile, 8 waves cover all 512 virtual cols (src|dst).
// blocks [nproj,...): degree counting (atomics), overlapped with the GEMM.
__global__ __launch_bounds__(512) void proj_mfma(
    const f16* __restrict__ feat_h,
    const f16* __restrict__ wsrc_h, const float* __restrict__ bsrc,
    const f16* __restrict__ wdst_h, const float* __restrict__ bdst,
    f16* __restrict__ fsrc_h, f16* __restrict__ fdst_h, int n,
    const int* __restrict__ dst, int* __restrict__ deg, int E, int nproj)
{
    if ((int)blockIdx.x >= nproj) {
        int i = ((int)blockIdx.x - nproj) * 512 + threadIdx.x;
        if (i < E) atomicAdd(&deg[dst[i]], 1);
        return;
    }
    const int t = threadIdx.x;
    const int lane = t & 63;
    const int w = t >> 6;
    const f16* __restrict__ W       = (w < 4) ? wsrc_h : wdst_h;
    const float* __restrict__ bias  = (w < 4) ? bsrc : bdst;
    f16* __restrict__ outp          = (w < 4) ? fsrc_h : fdst_h;
    const int col0 = (w & 3) * 64;
    const int row0 = blockIdx.x * 64;

    const int lr = lane & 15;
    const int kc = lane >> 4;    // k-chunk (8 f16 each)

    int brow[4];
    #pragma unroll
    for (int m = 0; m < 4; ++m) {
        int r = row0 + m * 16 + lr;
        brow[m] = (r < n) ? r : (n - 1);
    }

    f32x4 acc[4][4] = {};   // [nf][m]

    #pragma unroll
    for (int k0 = 0; k0 < N_DIN; k0 += 32) {
        f16x8 a[4], b[4];
        #pragma unroll
        for (int nf = 0; nf < 4; ++nf)
            a[nf] = *reinterpret_cast<const f16x8*>(
                &W[(size_t)(col0 + nf * 16 + lr) * N_DIN + k0 + kc * 8]);
        #pragma unroll
        for (int m = 0; m < 4; ++m)
            b[m] = *reinterpret_cast<const f16x8*>(
                &feat_h[(size_t)brow[m] * N_DIN + k0 + kc * 8]);
        #pragma unroll
        for (int nf = 0; nf < 4; ++nf)
            #pragma unroll
            for (int m = 0; m < 4; ++m)
                acc[nf][m] = __builtin_amdgcn_mfma_f32_16x16x32_f16(
                    a[nf], b[m], acc[nf][m], 0, 0, 0);
    }

    // D layout: col(lane&15)=feat row (output row); row((lane>>4)*4+r)=W row (output col)
    #pragma unroll
    for (int nf = 0; nf < 4; ++nf) {
        const int cbase = col0 + nf * 16 + kc * 4;
        const float4 bv = *reinterpret_cast<const float4*>(&bias[cbase]);
        #pragma unroll
        for (int m = 0; m < 4; ++m) {
            const int row = row0 + m * 16 + lr;
            if (row < n) {
                f16x4 o;
                o[0] = (f16)(acc[nf][m][0] + bv.x);
                o[1] = (f16)(acc[nf][m][1] + bv.y);
                o[2] = (f16)(acc[nf][m][2] + bv.z);
                o[3] = (f16)(acc[nf][m][3] + bv.w);
                *reinterpret_cast<f16x4*>(&outp[(size_t)row * N_COUT + cbase]) = o;
            }
        }
    }
}

// ---------------- CSR build: 3-phase parallel scan ----------------
__global__ __launch_bounds__(1024) void scan_part(
    const int* __restrict__ deg, int* __restrict__ offsets, int* __restrict__ bsum, int n)
{
    __shared__ int wsum[16];
    const int t = threadIdx.x, lane = t & 63, wv = t >> 6;
    const int i = blockIdx.x * 1024 + t;
    int v = (i < n) ? deg[i] : 0;
    int x = v;
    #pragma unroll
    for (int o = 1; o < 64; o <<= 1) {
        int y = __shfl_up(x, (unsigned)o);
        if (lane >= o) x += y;
    }
    if (lane == 63) wsum[wv] = x;
    __syncthreads();
    if (t < 16) {
        int s = wsum[t];
        #pragma unroll
        for (int o = 1; o < 16; o <<= 1) {
            int y = __shfl_up(s, (unsigned)o);
            if (t >= o) s += y;
        }
        wsum[t] = s;
    }
    __syncthreads();
    int wbase = wv ? wsum[wv - 1] : 0;
    if (i < n) offsets[i] = wbase + x - v;
    if (t == 0) bsum[blockIdx.x] = wsum[15];
}

__global__ __launch_bounds__(64) void scan_mid(
    int* __restrict__ bsum, int* __restrict__ offsets, int* __restrict__ ticket,
    int nb, int n)
{
    const int lane = threadIdx.x;
    if (lane == 0) *ticket = 0;            // re-zero work counter every call
    int v = (lane < nb) ? bsum[lane] : 0;
    int x = v;
    #pragma unroll
    for (int o = 1; o < 64; o <<= 1) {
        int y = __shfl_up(x, (unsigned)o);
        if (lane >= o) x += y;
    }
    if (lane < nb) bsum[lane] = x - v;
    if (lane == 63) offsets[n] = x;
}

__global__ __launch_bounds__(1024) void scan_add(
    const int* __restrict__ bsum, int* __restrict__ offsets, int* __restrict__ cursor, int n)
{
    int i = blockIdx.x * 1024 + threadIdx.x;
    if (i < n) {
        int o = offsets[i] + bsum[blockIdx.x];
        offsets[i] = o;
        cursor[i] = o;
    }
}

__global__ void scatter_edges(const int* __restrict__ src, const int* __restrict__ dst,
                              int* __restrict__ cursor, int* __restrict__ ssrc, int E)
{
    int i = blockIdx.x * 256 + threadIdx.x;
    if (i < E) {
        int d = dst[i];
        int pos = atomicAdd(&cursor[d], 1);
        ssrc[pos] = src[i];
    }
}

// ---------------- fused edge softmax + aggregation ----------------
// Persistent waves pop node tickets (perfect load balance). Lane owns dims
// [lane*4, lane*4+4); head = lane>>4. Packed-fp16 score path (pk_add/pk_max/
// pk_min/pk_fma + v_dot2_f32_f16), exp2 with log2e folded into attn,
// 4-edge quads with defer-max (T13).
__global__ __launch_bounds__(256) void gat_fused(
    const f16* __restrict__ fsrc_h, const f16* __restrict__ fdst_h,
    const float* __restrict__ attn, const int* __restrict__ offsets,
    const int* __restrict__ ssrc, int* __restrict__ ticket,
    float* __restrict__ out, int n)
{
    const int lane = threadIdx.x & 63;
    const int cb = lane * 4;

    const float4 awf = *reinterpret_cast<const float4*>(&attn[cb]);
    f16x2 aw01, aw23;
    aw01[0] = (f16)(awf.x * L2E); aw01[1] = (f16)(awf.y * L2E);
    aw23[0] = (f16)(awf.z * L2E); aw23[1] = (f16)(awf.w * L2E);
    const f16x2 zz = { (f16)0.f, (f16)0.f };
    const f16x2 slp = { (f16)NEG_SLOPE, (f16)NEG_SLOPE };

    for (;;) {
        int v;
        if (lane == 0) v = atomicAdd(ticket, 1);
        v = __shfl(v, 0);
        if (v >= n) break;

        f16x4 fdr = *reinterpret_cast<const f16x4*>(&fdst_h[(size_t)v * N_COUT + cb]);
        f16x2 fd01 = { fdr[0], fdr[1] };
        f16x2 fd23 = { fdr[2], fdr[3] };

        const int beg = offsets[v];
        const int end = offsets[v + 1];

        float m = -INFINITY, l = 0.f;
        float acc0 = 0.f, acc1 = 0.f, acc2 = 0.f, acc3 = 0.f;

        int j = beg;
        for (; j + 4 <= end; j += 4) {
            float f[4][4], s[4];
            #pragma unroll
            for (int q = 0; q < 4; ++q) {
                int u = ssrc[j + q];
                f16x4 fr = *reinterpret_cast<const f16x4*>(&fsrc_h[(size_t)u * N_COUT + cb]);
                f16x2 a01 = { fr[0], fr[1] };
                f16x2 a23 = { fr[2], fr[3] };
                f16x2 x01 = a01 + fd01;
                f16x2 x23 = a23 + fd23;
                f16x2 e01 = slp * __builtin_elementwise_min(x01, zz)
                          + __builtin_elementwise_max(x01, zz);
                f16x2 e23 = slp * __builtin_elementwise_min(x23, zz)
                          + __builtin_elementwise_max(x23, zz);
                s[q] = __builtin_amdgcn_fdot2(e23, aw23,
                        __builtin_amdgcn_fdot2(e01, aw01, 0.f, false), false);
                f[q][0] = (float)fr[0]; f[q][1] = (float)fr[1];
                f[q][2] = (float)fr[2]; f[q][3] = (float)fr[3];
            }
            #pragma unroll
            for (int o = 1; o < 16; o <<= 1) {
                s[0] += __shfl_xor(s[0], o);
                s[1] += __shfl_xor(s[1], o);
                s[2] += __shfl_xor(s[2], o);
                s[3] += __shfl_xor(s[3], o);
            }
            float mx = fmaxf(fmaxf(s[0], s[1]), fmaxf(s[2], s[3]));
            if (__all(mx <= m)) {
                float p0 = exp2f(s[0] - m), p1 = exp2f(s[1] - m);
                float p2 = exp2f(s[2] - m), p3 = exp2f(s[3] - m);
                l += (p0 + p1) + (p2 + p3);
                acc0 += fmaf(p0, f[0][0], p1 * f[1][0]) + fmaf(p2, f[2][0], p3 * f[3][0]);
                acc1 += fmaf(p0, f[0][1], p1 * f[1][1]) + fmaf(p2, f[2][1], p3 * f[3][1]);
                acc2 += fmaf(p0, f[0][2], p1 * f[1][2]) + fmaf(p2, f[2][2], p3 * f[3][2]);
                acc3 += fmaf(p0, f[0][3], p1 * f[1][3]) + fmaf(p2, f[2][3], p3 * f[3][3]);
            } else {
                float mnew = fmaxf(m, mx);
                float scale = exp2f(m - mnew);
                float p0 = exp2f(s[0] - mnew), p1 = exp2f(s[1] - mnew);
                float p2 = exp2f(s[2] - mnew), p3 = exp2f(s[3] - mnew);
                l = fmaf(l, scale, (p0 + p1) + (p2 + p3));
                acc0 = fmaf(acc0, scale, fmaf(p0, f[0][0], p1 * f[1][0]) + fmaf(p2, f[2][0], p3 * f[3][0]));
                acc1 = fmaf(acc1, scale, fmaf(p0, f[0][1], p1 * f[1][1]) + fmaf(p2, f[2][1], p3 * f[3][1]));
                acc2 = fmaf(acc2, scale, fmaf(p0, f[0][2], p1 * f[1][2]) + fmaf(p2, f[2][2], p3 * f[3][2]));
                acc3 = fmaf(acc3, scale, fmaf(p0, f[0][3], p1 * f[1][3]) + fmaf(p2, f[2][3], p3 * f[3][3]));
                m = mnew;
            }
        }
        for (; j < end; ++j) {
            int u = ssrc[j];
            f16x4 fr = *reinterpret_cast<const f16x4*>(&fsrc_h[(size_t)u * N_COUT + cb]);
            f16x2 a01 = { fr[0], fr[1] };
            f16x2 a23 = { fr[2], fr[3] };
            f16x2 x01 = a01 + fd01;
            f16x2 x23 = a23 + fd23;
            f16x2 e01 = slp * __builtin_elementwise_min(x01, zz)
                      + __builtin_elementwise_max(x01, zz);
            f16x2 e23 = slp * __builtin_elementwise_min(x23, zz)
                      + __builtin_elementwise_max(x23, zz);
            float sa = __builtin_amdgcn_fdot2(e23, aw23,
                        __builtin_amdgcn_fdot2(e01, aw01, 0.f, false), false);
            sa += __shfl_xor(sa, 1);
            sa += __shfl_xor(sa, 2);
            sa += __shfl_xor(sa, 4);
            sa += __shfl_xor(sa, 8);
            float mnew = fmaxf(m, sa);
            float scale = exp2f(m - mnew);
            float pa = exp2f(sa - mnew);
            l = fmaf(l, scale, pa);
            acc0 = fmaf(acc0, scale, pa * (float)fr[0]);
            acc1 = fmaf(acc1, scale, pa * (float)fr[1]);
            acc2 = fmaf(acc2, scale, pa * (float)fr[2]);
            acc3 = fmaf(acc3, scale, pa * (float)fr[3]);
            m = mnew;
        }

        const float inv = (l > 0.f) ? (1.0f / l) : 0.f;
        float4 o = make_float4(acc0 * inv, acc1 * inv, acc2 * inv, acc3 * inv);
        *reinterpret_cast<float4*>(&out[(size_t)v * N_COUT + cb]) = o;
    }
}

// ---------------- launch ----------------
extern "C" void kernel_launch(void* const* d_in, const int* in_sizes, int n_in,
                              void* d_out, int out_size, void* d_ws, size_t ws_size,
                              hipStream_t stream)
{
    const float* feat = (const float*)d_in[0];
    const int*   src  = (const int*)d_in[1];
    const int*   dst  = (const int*)d_in[2];
    const float* Wsrc = (const float*)d_in[3];
    const float* bsrc = (const float*)d_in[4];
    const float* Wdst = (const float*)d_in[5];
    const float* bdst = (const float*)d_in[6];
    const float* attn = (const float*)d_in[7];

    const int N = in_sizes[0] / N_DIN;     // 50000
    const int E = in_sizes[1];             // 800000
    float* out = (float*)d_out;

    // workspace layout (16B-aligned)
    char* ws = (char*)d_ws;
    f16* feat_h = (f16*)ws; ws += (size_t)N * N_DIN * sizeof(f16);
    f16* wsrc_h = (f16*)ws; ws += (size_t)N_COUT * N_DIN * sizeof(f16);
    f16* wdst_h = (f16*)ws; ws += (size_t)N_COUT * N_DIN * sizeof(f16);
    f16* fsrc_h = (f16*)ws; ws += (size_t)N * N_COUT * sizeof(f16);
    f16* fdst_h = (f16*)ws; ws += (size_t)N * N_COUT * sizeof(f16);
    int* offsets = (int*)ws;  ws += (size_t)(N + 64) * sizeof(int);
    int* cursor  = (int*)ws;  ws += (size_t)N * sizeof(int);
    int* bsum    = (int*)ws;  ws += 64 * sizeof(int);
    int* ticket  = (int*)ws;  ws += 16 * sizeof(int);
    int* ssrc    = (int*)ws;  ws += (size_t)E * sizeof(int);

    const int nscan = (N + 1023) / 1024;       // 49
    const int nproj = (N + 63) / 64;           // 782
    const int ncnt  = (E + 511) / 512;         // 1563

    // 1) convert feat/W to fp16 + zero cursor
    convert_all<<<6314 + (N + 255) / 256, 256, 0, stream>>>(
        feat, Wsrc, Wdst, feat_h, wsrc_h, wdst_h, cursor, N);

    // 2) fp16 MFMA projections + fused degree count
    proj_mfma<<<nproj + ncnt, 512, 0, stream>>>(feat_h, wsrc_h, bsrc, wdst_h, bdst,
                                                fsrc_h, fdst_h, N, dst, cursor, E, nproj);

    // 3) CSR by dst (parallel 3-phase scan) + scatter
    scan_part<<<nscan, 1024, 0, stream>>>(cursor, offsets, bsum, N);
    scan_mid<<<1, 64, 0, stream>>>(bsum, offsets, ticket, nscan, N);
    scan_add<<<nscan, 1024, 0, stream>>>(bsum, offsets, cursor, N);
    scatter_edges<<<(E + 255) / 256, 256, 0, stream>>>(src, dst, cursor, ssrc, E);

    // 4) fused edge softmax + aggregation (persistent waves)
    gat_fused<<<2048, 256, 0, stream>>>(fsrc_h, fdst_h, attn, offsets, ssrc, ticket, out, N);
}

// Round 6
// 257.695 us; speedup vs baseline: 3.2516x; 3.2516x over previous
//
#include <hip/hip_runtime.h>
#include <hip/hip_bf16.h>
#include <math.h>

#define N_DIN 256      // D_IN
#define N_COUT 256     // H*D_OUT
#define NEG_SLOPE 0.2f
#define L2E 1.44269504f   // log2(e)

typedef _Float16 f16;
typedef f16 f16x2 __attribute__((ext_vector_type(2)));
typedef f16 f16x4 __attribute__((ext_vector_type(4)));
typedef f16 f16x8 __attribute__((ext_vector_type(8)));
typedef float f32x4 __attribute__((ext_vector_type(4)));

// ---------------- fp32 -> fp16 conversion (feat, Wsrc, Wdst) + cursor zeroing ----------------
// grid: [0,6250) feat, [6250,6282) Wsrc, [6282,6314) Wdst, [6314,...) zero cursor
__global__ __launch_bounds__(256) void convert_all(
    const float* __restrict__ feat, const float* __restrict__ Wsrc,
    const float* __restrict__ Wdst, f16* __restrict__ feat_h,
    f16* __restrict__ wsrc_h, f16* __restrict__ wdst_h,
    int* __restrict__ cursor, int n)
{
    const int b = blockIdx.x;
    if (b >= 6314) {
        int i = (b - 6314) * 256 + threadIdx.x;
        if (i < n) cursor[i] = 0;
        return;
    }
    const float* __restrict__ in;
    f16* __restrict__ out;
    size_t base;
    if (b < 6250)      { in = feat; out = feat_h; base = (size_t)b * 2048; }
    else if (b < 6282) { in = Wsrc; out = wsrc_h; base = (size_t)(b - 6250) * 2048; }
    else               { in = Wdst; out = wdst_h; base = (size_t)(b - 6282) * 2048; }
    size_t i = base + (size_t)threadIdx.x * 8;
    float4 v0 = *reinterpret_cast<const float4*>(&in[i]);
    float4 v1 = *reinterpret_cast<const float4*>(&in[i + 4]);
    f16x8 o;
    o[0] = (f16)v0.x; o[1] = (f16)v0.y; o[2] = (f16)v0.z; o[3] = (f16)v0.w;
    o[4] = (f16)v1.x; o[5] = (f16)v1.y; o[6] = (f16)v1.z; o[7] = (f16)v1.w;
    *reinterpret_cast<f16x8*>(&out[i]) = o;
}

// ---------------- fp16 MFMA projection + fused degree count ----------------
// blocks [0,nproj): 64-row tile, 8 waves cover all 512 virtual cols (src|dst).
// blocks [nproj,...): degree counting (atomics), overlapped with the GEMM.
__global__ __launch_bounds__(512) void proj_mfma(
    const f16* __restrict__ feat_h,
    const f16* __restrict__ wsrc_h, const float* __restrict__ bsrc,
    const f16* __restrict__ wdst_h, const float* __restrict__ bdst,
    f16* __restrict__ fsrc_h, f16* __restrict__ fdst_h, int n,
    const int* __restrict__ dst, int* __restrict__ deg, int E, int nproj)
{
    if ((int)blockIdx.x >= nproj) {
        int i = ((int)blockIdx.x - nproj) * 512 + threadIdx.x;
        if (i < E) atomicAdd(&deg[dst[i]], 1);
        return;
    }
    const int t = threadIdx.x;
    const int lane = t & 63;
    const int w = t >> 6;
    const f16* __restrict__ W       = (w < 4) ? wsrc_h : wdst_h;
    const float* __restrict__ bias  = (w < 4) ? bsrc : bdst;
    f16* __restrict__ outp          = (w < 4) ? fsrc_h : fdst_h;
    const int col0 = (w & 3) * 64;
    const int row0 = blockIdx.x * 64;

    const int lr = lane & 15;
    const int kc = lane >> 4;    // k-chunk (8 f16 each)

    int brow[4];
    #pragma unroll
    for (int m = 0; m < 4; ++m) {
        int r = row0 + m * 16 + lr;
        brow[m] = (r < n) ? r : (n - 1);
    }

    f32x4 acc[4][4] = {};   // [nf][m]

    #pragma unroll
    for (int k0 = 0; k0 < N_DIN; k0 += 32) {
        f16x8 a[4], b[4];
        #pragma unroll
        for (int nf = 0; nf < 4; ++nf)
            a[nf] = *reinterpret_cast<const f16x8*>(
                &W[(size_t)(col0 + nf * 16 + lr) * N_DIN + k0 + kc * 8]);
        #pragma unroll
        for (int m = 0; m < 4; ++m)
            b[m] = *reinterpret_cast<const f16x8*>(
                &feat_h[(size_t)brow[m] * N_DIN + k0 + kc * 8]);
        #pragma unroll
        for (int nf = 0; nf < 4; ++nf)
            #pragma unroll
            for (int m = 0; m < 4; ++m)
                acc[nf][m] = __builtin_amdgcn_mfma_f32_16x16x32_f16(
                    a[nf], b[m], acc[nf][m], 0, 0, 0);
    }

    // D layout: col(lane&15)=feat row (output row); row((lane>>4)*4+r)=W row (output col)
    #pragma unroll
    for (int nf = 0; nf < 4; ++nf) {
        const int cbase = col0 + nf * 16 + kc * 4;
        const float4 bv = *reinterpret_cast<const float4*>(&bias[cbase]);
        #pragma unroll
        for (int m = 0; m < 4; ++m) {
            const int row = row0 + m * 16 + lr;
            if (row < n) {
                f16x4 o;
                o[0] = (f16)(acc[nf][m][0] + bv.x);
                o[1] = (f16)(acc[nf][m][1] + bv.y);
                o[2] = (f16)(acc[nf][m][2] + bv.z);
                o[3] = (f16)(acc[nf][m][3] + bv.w);
                *reinterpret_cast<f16x4*>(&outp[(size_t)row * N_COUT + cbase]) = o;
            }
        }
    }
}

// ---------------- CSR build: 3-phase parallel scan ----------------
__global__ __launch_bounds__(1024) void scan_part(
    const int* __restrict__ deg, int* __restrict__ offsets, int* __restrict__ bsum, int n)
{
    __shared__ int wsum[16];
    const int t = threadIdx.x, lane = t & 63, wv = t >> 6;
    const int i = blockIdx.x * 1024 + t;
    int v = (i < n) ? deg[i] : 0;
    int x = v;
    #pragma unroll
    for (int o = 1; o < 64; o <<= 1) {
        int y = __shfl_up(x, (unsigned)o);
        if (lane >= o) x += y;
    }
    if (lane == 63) wsum[wv] = x;
    __syncthreads();
    if (t < 16) {
        int s = wsum[t];
        #pragma unroll
        for (int o = 1; o < 16; o <<= 1) {
            int y = __shfl_up(s, (unsigned)o);
            if (t >= o) s += y;
        }
        wsum[t] = s;
    }
    __syncthreads();
    int wbase = wv ? wsum[wv - 1] : 0;
    if (i < n) offsets[i] = wbase + x - v;
    if (t == 0) bsum[blockIdx.x] = wsum[15];
}

__global__ __launch_bounds__(64) void scan_mid(
    int* __restrict__ bsum, int* __restrict__ offsets, int nb, int n)
{
    const int lane = threadIdx.x;
    int v = (lane < nb) ? bsum[lane] : 0;
    int x = v;
    #pragma unroll
    for (int o = 1; o < 64; o <<= 1) {
        int y = __shfl_up(x, (unsigned)o);
        if (lane >= o) x += y;
    }
    if (lane < nb) bsum[lane] = x - v;
    if (lane == 63) offsets[n] = x;
}

__global__ __launch_bounds__(1024) void scan_add(
    const int* __restrict__ bsum, int* __restrict__ offsets, int* __restrict__ cursor, int n)
{
    int i = blockIdx.x * 1024 + threadIdx.x;
    if (i < n) {
        int o = offsets[i] + bsum[blockIdx.x];
        offsets[i] = o;
        cursor[i] = o;
    }
}

__global__ void scatter_edges(const int* __restrict__ src, const int* __restrict__ dst,
                              int* __restrict__ cursor, int* __restrict__ ssrc, int E)
{
    int i = blockIdx.x * 256 + threadIdx.x;
    if (i < E) {
        int d = dst[i];
        int pos = atomicAdd(&cursor[d], 1);
        ssrc[pos] = src[i];
    }
}

// ---------------- fused edge softmax + aggregation ----------------
// Wave-level grid-stride over nodes (no atomics, no inter-node dependency):
// wave g handles nodes {g, g+NW, ...}. Lane owns dims [lane*4, lane*4+4);
// head = lane>>4. Packed-fp16 score path + v_dot2_f32_f16, exp2 with log2e
// folded into attn, 4-edge quads with defer-max (T13).
__global__ __launch_bounds__(256) void gat_grid(
    const f16* __restrict__ fsrc_h, const f16* __restrict__ fdst_h,
    const float* __restrict__ attn, const int* __restrict__ offsets,
    const int* __restrict__ ssrc, float* __restrict__ out, int n, int nwaves)
{
    const int lane = threadIdx.x & 63;
    const int gw = blockIdx.x * 4 + (threadIdx.x >> 6);
    const int cb = lane * 4;

    const float4 awf = *reinterpret_cast<const float4*>(&attn[cb]);
    f16x2 aw01, aw23;
    aw01[0] = (f16)(awf.x * L2E); aw01[1] = (f16)(awf.y * L2E);
    aw23[0] = (f16)(awf.z * L2E); aw23[1] = (f16)(awf.w * L2E);
    const f16x2 zz = { (f16)0.f, (f16)0.f };
    const f16x2 slp = { (f16)NEG_SLOPE, (f16)NEG_SLOPE };

    for (int v = gw; v < n; v += nwaves) {
        f16x4 fdr = *reinterpret_cast<const f16x4*>(&fdst_h[(size_t)v * N_COUT + cb]);
        f16x2 fd01 = { fdr[0], fdr[1] };
        f16x2 fd23 = { fdr[2], fdr[3] };

        const int beg = offsets[v];
        const int end = offsets[v + 1];

        float m = -INFINITY, l = 0.f;
        float acc0 = 0.f, acc1 = 0.f, acc2 = 0.f, acc3 = 0.f;

        int j = beg;
        for (; j + 4 <= end; j += 4) {
            float f[4][4], s[4];
            #pragma unroll
            for (int q = 0; q < 4; ++q) {
                int u = ssrc[j + q];
                f16x4 fr = *reinterpret_cast<const f16x4*>(&fsrc_h[(size_t)u * N_COUT + cb]);
                f16x2 a01 = { fr[0], fr[1] };
                f16x2 a23 = { fr[2], fr[3] };
                f16x2 x01 = a01 + fd01;
                f16x2 x23 = a23 + fd23;
                f16x2 e01 = slp * __builtin_elementwise_min(x01, zz)
                          + __builtin_elementwise_max(x01, zz);
                f16x2 e23 = slp * __builtin_elementwise_min(x23, zz)
                          + __builtin_elementwise_max(x23, zz);
                s[q] = __builtin_amdgcn_fdot2(e23, aw23,
                        __builtin_amdgcn_fdot2(e01, aw01, 0.f, false), false);
                f[q][0] = (float)fr[0]; f[q][1] = (float)fr[1];
                f[q][2] = (float)fr[2]; f[q][3] = (float)fr[3];
            }
            #pragma unroll
            for (int o = 1; o < 16; o <<= 1) {
                s[0] += __shfl_xor(s[0], o);
                s[1] += __shfl_xor(s[1], o);
                s[2] += __shfl_xor(s[2], o);
                s[3] += __shfl_xor(s[3], o);
            }
            float mx = fmaxf(fmaxf(s[0], s[1]), fmaxf(s[2], s[3]));
            if (__all(mx <= m)) {
                float p0 = exp2f(s[0] - m), p1 = exp2f(s[1] - m);
                float p2 = exp2f(s[2] - m), p3 = exp2f(s[3] - m);
                l += (p0 + p1) + (p2 + p3);
                acc0 += fmaf(p0, f[0][0], p1 * f[1][0]) + fmaf(p2, f[2][0], p3 * f[3][0]);
                acc1 += fmaf(p0, f[0][1], p1 * f[1][1]) + fmaf(p2, f[2][1], p3 * f[3][1]);
                acc2 += fmaf(p0, f[0][2], p1 * f[1][2]) + fmaf(p2, f[2][2], p3 * f[3][2]);
                acc3 += fmaf(p0, f[0][3], p1 * f[1][3]) + fmaf(p2, f[2][3], p3 * f[3][3]);
            } else {
                float mnew = fmaxf(m, mx);
                float scale = exp2f(m - mnew);
                float p0 = exp2f(s[0] - mnew), p1 = exp2f(s[1] - mnew);
                float p2 = exp2f(s[2] - mnew), p3 = exp2f(s[3] - mnew);
                l = fmaf(l, scale, (p0 + p1) + (p2 + p3));
                acc0 = fmaf(acc0, scale, fmaf(p0, f[0][0], p1 * f[1][0]) + fmaf(p2, f[2][0], p3 * f[3][0]));
                acc1 = fmaf(acc1, scale, fmaf(p0, f[0][1], p1 * f[1][1]) + fmaf(p2, f[2][1], p3 * f[3][1]));
                acc2 = fmaf(acc2, scale, fmaf(p0, f[0][2], p1 * f[1][2]) + fmaf(p2, f[2][2], p3 * f[3][2]));
                acc3 = fmaf(acc3, scale, fmaf(p0, f[0][3], p1 * f[1][3]) + fmaf(p2, f[2][3], p3 * f[3][3]));
                m = mnew;
            }
        }
        for (; j < end; ++j) {
            int u = ssrc[j];
            f16x4 fr = *reinterpret_cast<const f16x4*>(&fsrc_h[(size_t)u * N_COUT + cb]);
            f16x2 a01 = { fr[0], fr[1] };
            f16x2 a23 = { fr[2], fr[3] };
            f16x2 x01 = a01 + fd01;
            f16x2 x23 = a23 + fd23;
            f16x2 e01 = slp * __builtin_elementwise_min(x01, zz)
                      + __builtin_elementwise_max(x01, zz);
            f16x2 e23 = slp * __builtin_elementwise_min(x23, zz)
                      + __builtin_elementwise_max(x23, zz);
            float sa = __builtin_amdgcn_fdot2(e23, aw23,
                        __builtin_amdgcn_fdot2(e01, aw01, 0.f, false), false);
            sa += __shfl_xor(sa, 1);
            sa += __shfl_xor(sa, 2);
            sa += __shfl_xor(sa, 4);
            sa += __shfl_xor(sa, 8);
            float mnew = fmaxf(m, sa);
            float scale = exp2f(m - mnew);
            float pa = exp2f(sa - mnew);
            l = fmaf(l, scale, pa);
            acc0 = fmaf(acc0, scale, pa * (float)fr[0]);
            acc1 = fmaf(acc1, scale, pa * (float)fr[1]);
            acc2 = fmaf(acc2, scale, pa * (float)fr[2]);
            acc3 = fmaf(acc3, scale, pa * (float)fr[3]);
            m = mnew;
        }

        const float inv = (l > 0.f) ? (1.0f / l) : 0.f;
        float4 o = make_float4(acc0 * inv, acc1 * inv, acc2 * inv, acc3 * inv);
        *reinterpret_cast<float4*>(&out[(size_t)v * N_COUT + cb]) = o;
    }
}

// ---------------- launch ----------------
extern "C" void kernel_launch(void* const* d_in, const int* in_sizes, int n_in,
                              void* d_out, int out_size, void* d_ws, size_t ws_size,
                              hipStream_t stream)
{
    const float* feat = (const float*)d_in[0];
    const int*   src  = (const int*)d_in[1];
    const int*   dst  = (const int*)d_in[2];
    const float* Wsrc = (const float*)d_in[3];
    const float* bsrc = (const float*)d_in[4];
    const float* Wdst = (const float*)d_in[5];
    const float* bdst = (const float*)d_in[6];
    const float* attn = (const float*)d_in[7];

    const int N = in_sizes[0] / N_DIN;     // 50000
    const int E = in_sizes[1];             // 800000
    float* out = (float*)d_out;

    // workspace layout (16B-aligned)
    char* ws = (char*)d_ws;
    f16* feat_h = (f16*)ws; ws += (size_t)N * N_DIN * sizeof(f16);
    f16* wsrc_h = (f16*)ws; ws += (size_t)N_COUT * N_DIN * sizeof(f16);
    f16* wdst_h = (f16*)ws; ws += (size_t)N_COUT * N_DIN * sizeof(f16);
    f16* fsrc_h = (f16*)ws; ws += (size_t)N * N_COUT * sizeof(f16);
    f16* fdst_h = (f16*)ws; ws += (size_t)N * N_COUT * sizeof(f16);
    int* offsets = (int*)ws;  ws += (size_t)(N + 64) * sizeof(int);
    int* cursor  = (int*)ws;  ws += (size_t)N * sizeof(int);
    int* bsum    = (int*)ws;  ws += 64 * sizeof(int);
    int* ssrc    = (int*)ws;  ws += (size_t)E * sizeof(int);

    const int nscan = (N + 1023) / 1024;       // 49
    const int nproj = (N + 63) / 64;           // 782
    const int ncnt  = (E + 511) / 512;         // 1563

    // 1) convert feat/W to fp16 + zero cursor
    convert_all<<<6314 + (N + 255) / 256, 256, 0, stream>>>(
        feat, Wsrc, Wdst, feat_h, wsrc_h, wdst_h, cursor, N);

    // 2) fp16 MFMA projections + fused degree count
    proj_mfma<<<nproj + ncnt, 512, 0, stream>>>(feat_h, wsrc_h, bsrc, wdst_h, bdst,
                                                fsrc_h, fdst_h, N, dst, cursor, E, nproj);

    // 3) CSR by dst (parallel 3-phase scan) + scatter
    scan_part<<<nscan, 1024, 0, stream>>>(cursor, offsets, bsum, N);
    scan_mid<<<1, 64, 0, stream>>>(bsum, offsets, nscan, N);
    scan_add<<<nscan, 1024, 0, stream>>>(bsum, offsets, cursor, N);
    scatter_edges<<<(E + 255) / 256, 256, 0, stream>>>(src, dst, cursor, ssrc, E);

    // 4) fused edge softmax + aggregation (wave-level grid-stride, 8192 waves)
    const int nblocks = 2048;
    gat_grid<<<nblocks, 256, 0, stream>>>(fsrc_h, fdst_h, attn, offsets, ssrc, out, N,
                                          nblocks * 4);
}